// Round 12
// baseline (49.638 us; speedup 1.0000x reference)
//
#include <hip/hip_runtime.h>
#include <math.h>

#define LDIM 64
#define QT 32    // queries per tile (block)
#define QW 8     // queries per wave
#define LOG2E 1.4426950408889634f

static __device__ __forceinline__ float fast_exp2(float x) {
#if __has_builtin(__builtin_amdgcn_exp2f)
    return __builtin_amdgcn_exp2f(x);
#else
    return exp2f(x);
#endif
}

static __device__ __forceinline__ float4 ld4(const float* p) {
    return *(const float4*)p;
}

// K1: fused logits + softmax(no-max) + PV accumulate, one (32-query tile,
// 64-obs chunk) per block. Key changes vs R9:
//  - PV lane mapping = (obs-group og = lane>>4, k-quad k4 = lane&15):
//    H chunk loaded as 16 float4 per wave (was 64 scalar loads), ALL issued
//    before the logits phase so ~500 fma hide the memory latency.
//  - den partials accumulated per-lane, reduced once at wave end.
//  - acc merged across og via shfl_xor(16|32), lane<16 does the atomics.
// Plain fire-and-forget atomics (R8: no fences). No-max exp2 (R6-R11).
__global__ __launch_bounds__(256) void gano_accum(
    const float* __restrict__ h_obs,
    const float* __restrict__ pos_obs, const float* __restrict__ pos_query,
    const float* __restrict__ W1, const float* __restrict__ b1,
    const float* __restrict__ W2,
    const int* __restrict__ obs_mask, const int* __restrict__ obs_batch,
    const int* __restrict__ query_batch,
    float* __restrict__ acc, float* __restrict__ den,
    int No, int Nq)
{
    const int t   = blockIdx.x;          // query tile (fast dim: neighbors share chunk reads)
    const int c   = blockIdx.y;          // obs chunk
    const int q0  = t * QT;
    const int tid = threadIdx.x, lane = tid & 63, wid = tid >> 6;

    if ((c << 6) >= No) return;
    // batch-span intersection early-exit (both arrays sorted): 4 loads
    const int c_lo = obs_batch[c << 6];
    const int c_hi = obs_batch[min((c << 6) + 63, No - 1)];
    const int t_lo = query_batch[min(q0, Nq - 1)];
    const int t_hi = query_batch[min(q0 + QT - 1, Nq - 1)];
    if (c_lo > t_hi || c_hi < t_lo) return;

    __shared__ float4 B4[16][64];       // [g][o] obs-side preact chunk (16KB)
    __shared__ float4 a4[QT][16];       // [q][g] query-side preact (8KB)
    __shared__ float4 w2l[16];          // W2 * log2e
    __shared__ float4 qp4[QT];          // (x,y,z, batch+1)
    __shared__ float  e_lds[4][QW][LDIM]; // wave-private e rows (8KB)

    // ---- staging: a4 (2 entries/thread) ----
    #pragma unroll
    for (int rep = 0; rep < 2; ++rep) {
        const int i = tid + rep * 256;
        const int q = i >> 4, g = i & 15;
        const int qq = min(q0 + q, Nq - 1);
        const float px = pos_query[qq*3+0], py = pos_query[qq*3+1], pz = pos_query[qq*3+2];
        const float4 u0 = ld4(W1 + 0*LDIM + 4*g), u6 = ld4(W1 + 6*LDIM + 4*g);
        const float4 u1 = ld4(W1 + 1*LDIM + 4*g), u7 = ld4(W1 + 7*LDIM + 4*g);
        const float4 u2 = ld4(W1 + 2*LDIM + 4*g), u8 = ld4(W1 + 8*LDIM + 4*g);
        float4 r;
        r.x = fmaf(px, u0.x+u6.x, fmaf(py, u1.x+u7.x, pz*(u2.x+u8.x)));
        r.y = fmaf(px, u0.y+u6.y, fmaf(py, u1.y+u7.y, pz*(u2.y+u8.y)));
        r.z = fmaf(px, u0.z+u6.z, fmaf(py, u1.z+u7.z, pz*(u2.z+u8.z)));
        r.w = fmaf(px, u0.w+u6.w, fmaf(py, u1.w+u7.w, pz*(u2.w+u8.w)));
        a4[q][g] = r;
    }
    if (tid < 16) {
        const float4 w = ld4(W2 + 4 * tid);
        w2l[tid] = make_float4(w.x * LOG2E, w.y * LOG2E, w.z * LOG2E, w.w * LOG2E);
    }
    if (tid < QT) {
        const int q = min(q0 + tid, Nq - 1);
        qp4[tid] = make_float4(pos_query[q*3+0], pos_query[q*3+1], pos_query[q*3+2],
                               (float)(query_batch[q] + 1));
    }
    // ---- staging: B4, lane = obs, 4 g per wave ----
    const int oo = (c << 6) + lane;
    float px = 0.f, py = 0.f, pz = 0.f, pcode = 0.f;
    if (oo < No) {
        px = pos_obs[oo*3+0]; py = pos_obs[oo*3+1]; pz = pos_obs[oo*3+2];
        pcode = obs_mask[oo] ? (float)(obs_batch[oo] + 1) : 0.0f;
    }
    #pragma unroll
    for (int k = 0; k < 4; ++k) {
        const int g = wid * 4 + k;
        const float4 b0 = ld4(b1 + 4*g);
        const float4 u3 = ld4(W1 + 3*LDIM + 4*g), u6 = ld4(W1 + 6*LDIM + 4*g);
        const float4 u4 = ld4(W1 + 4*LDIM + 4*g), u7 = ld4(W1 + 7*LDIM + 4*g);
        const float4 u5 = ld4(W1 + 5*LDIM + 4*g), u8 = ld4(W1 + 8*LDIM + 4*g);
        float4 r;
        r.x = fmaf(px, u3.x-u6.x, fmaf(py, u4.x-u7.x, fmaf(pz, u5.x-u8.x, b0.x)));
        r.y = fmaf(px, u3.y-u6.y, fmaf(py, u4.y-u7.y, fmaf(pz, u5.y-u8.y, b0.y)));
        r.z = fmaf(px, u3.z-u6.z, fmaf(py, u4.z-u7.z, fmaf(pz, u5.z-u8.z, b0.z)));
        r.w = fmaf(px, u3.w-u6.w, fmaf(py, u4.w-u7.w, fmaf(pz, u5.w-u8.w, b0.w)));
        B4[g][lane] = r;
    }
    __syncthreads();

    // ---- H prefetch: issue ALL 16 float4 loads now; consumed after logits ----
    const int og = lane >> 4, k4 = lane & 15;
    float4 H4[16];
    if ((c << 6) + 64 <= No) {
        const float* Hb = h_obs + (((size_t)(c << 6) + (og << 4)) << 6) + (k4 << 2);
        #pragma unroll
        for (int i = 0; i < 16; ++i) H4[i] = ld4(Hb + ((size_t)i << 6));
    } else {  // tail chunk: clamp rows (e = 0 there)
        #pragma unroll
        for (int i = 0; i < 16; ++i) {
            const int orow = min((c << 6) + (og << 4) + i, No - 1);
            H4[i] = ld4(h_obs + ((size_t)orow << 6) + (k4 << 2));
        }
    }

    // ---- logits: lane = obs, 8 queries ----
    float lg[QW];
    #pragma unroll
    for (int j = 0; j < QW; ++j) lg[j] = 0.0f;
    #pragma unroll
    for (int g = 0; g < 16; ++g) {
        const float4 Bv = B4[g][lane];
        const float4 wv = w2l[g];
        #pragma unroll
        for (int j = 0; j < QW; ++j) {
            const float4 a = a4[wid * QW + j][g];
            lg[j] = fmaf(fmaxf(a.x + Bv.x, 0.f), wv.x, lg[j]);
            lg[j] = fmaf(fmaxf(a.y + Bv.y, 0.f), wv.y, lg[j]);
            lg[j] = fmaf(fmaxf(a.z + Bv.z, 0.f), wv.z, lg[j]);
            lg[j] = fmaf(fmaxf(a.w + Bv.w, 0.f), wv.w, lg[j]);
        }
    }

    // ---- mask + direct exp2; e to wave-private LDS; den per-lane partials ----
    float den_a[QW];
    #pragma unroll
    for (int j = 0; j < QW; ++j) {
        const float4 qp = qp4[wid * QW + j];
        const float dx = qp.x - px, dy = qp.y - py, dz = qp.z - pz;
        const float d2 = fmaf(dz, dz, fmaf(dy, dy, dx * dx));
        const bool valid = (pcode == qp.w) & (d2 <= 1.0f);
        const float e = valid ? fast_exp2(lg[j]) : 0.0f;
        e_lds[wid][j][lane] = e;
        den_a[j] = e;
    }

    // ---- PV: lane = (og, k4); pure register fma on prefetched H4 ----
    float4 acc4[QW];
    #pragma unroll
    for (int j = 0; j < QW; ++j) acc4[j] = make_float4(0.f, 0.f, 0.f, 0.f);
    #pragma unroll
    for (int s = 0; s < 4; ++s) {
        float4 e4[QW];
        #pragma unroll
        for (int j = 0; j < QW; ++j)
            e4[j] = *(const float4*)&e_lds[wid][j][(og << 4) + (s << 2)];
        const float4 h0 = H4[(s << 2) + 0];
        const float4 h1 = H4[(s << 2) + 1];
        const float4 h2 = H4[(s << 2) + 2];
        const float4 h3 = H4[(s << 2) + 3];
        #pragma unroll
        for (int j = 0; j < QW; ++j) {
            float4 v = acc4[j];
            v.x = fmaf(e4[j].x, h0.x, v.x); v.y = fmaf(e4[j].x, h0.y, v.y);
            v.z = fmaf(e4[j].x, h0.z, v.z); v.w = fmaf(e4[j].x, h0.w, v.w);
            v.x = fmaf(e4[j].y, h1.x, v.x); v.y = fmaf(e4[j].y, h1.y, v.y);
            v.z = fmaf(e4[j].y, h1.z, v.z); v.w = fmaf(e4[j].y, h1.w, v.w);
            v.x = fmaf(e4[j].z, h2.x, v.x); v.y = fmaf(e4[j].z, h2.y, v.y);
            v.z = fmaf(e4[j].z, h2.z, v.z); v.w = fmaf(e4[j].z, h2.w, v.w);
            v.x = fmaf(e4[j].w, h3.x, v.x); v.y = fmaf(e4[j].w, h3.y, v.y);
            v.z = fmaf(e4[j].w, h3.z, v.z); v.w = fmaf(e4[j].w, h3.w, v.w);
            acc4[j] = v;
        }
    }

    // ---- den: single end reduce + atomics ----
    #pragma unroll
    for (int msk = 32; msk; msk >>= 1) {
        #pragma unroll
        for (int j = 0; j < QW; ++j) den_a[j] += __shfl_xor(den_a[j], msk, 64);
    }
    if (lane == 0) {
        #pragma unroll
        for (int j = 0; j < QW; ++j) {
            const int q = q0 + wid * QW + j;
            if (q < Nq) atomicAdd(&den[q], den_a[j]);
        }
    }

    // ---- acc: merge og groups via shfl, lane<16 atomics (4 consecutive k) ----
    #pragma unroll
    for (int j = 0; j < QW; ++j) {
        float4 v = acc4[j];
        v.x += __shfl_xor(v.x, 16, 64); v.y += __shfl_xor(v.y, 16, 64);
        v.z += __shfl_xor(v.z, 16, 64); v.w += __shfl_xor(v.w, 16, 64);
        v.x += __shfl_xor(v.x, 32, 64); v.y += __shfl_xor(v.y, 32, 64);
        v.z += __shfl_xor(v.z, 32, 64); v.w += __shfl_xor(v.w, 32, 64);
        const int q = q0 + wid * QW + j;
        if (lane < 16 && q < Nq) {
            float* dst = acc + (size_t)q * LDIM + (k4 << 2);
            atomicAdd(dst + 0, v.x);
            atomicAdd(dst + 1, v.y);
            atomicAdd(dst + 2, v.z);
            atomicAdd(dst + 3, v.w);
        }
    }
}

// K2: normalize + Wv epilogue + bv.  out[q] = (acc[q]/D) @ Wv + bv, or 0 if D==0.
__global__ __launch_bounds__(256) void gano_norm(
    const float* __restrict__ acc, const float* __restrict__ den,
    const float* __restrict__ Wv, const float* __restrict__ bv,
    float* __restrict__ out, int Nq)
{
    const int tid = threadIdx.x, lane = tid & 63, wid = tid >> 6;
    const int q0 = blockIdx.x * 8 + wid * 2;
    if (q0 >= Nq) return;

    __shared__ float r_lds[4][2][LDIM];

    const float D0 = den[q0];
    const float D1 = (q0 + 1 < Nq) ? den[q0 + 1] : 0.0f;
    const float rd0 = (D0 > 0.0f) ? 1.0f / D0 : 0.0f;
    const float rd1 = (D1 > 0.0f) ? 1.0f / D1 : 0.0f;
    r_lds[wid][0][lane] = acc[(size_t)q0 * LDIM + lane] * rd0;
    r_lds[wid][1][lane] = (q0 + 1 < Nq) ? acc[(size_t)(q0 + 1) * LDIM + lane] * rd1 : 0.0f;
    // wave-private: no barrier needed
    float o0 = 0.f, o1 = 0.f;
    #pragma unroll 8
    for (int k = 0; k < LDIM; ++k) {
        const float w = Wv[(k << 6) + lane];
        o0 = fmaf(r_lds[wid][0][k], w, o0);
        o1 = fmaf(r_lds[wid][1][k], w, o1);
    }
    const float b = bv[lane];
    out[(size_t)q0 * LDIM + lane] = (D0 > 0.0f) ? o0 + b : 0.0f;
    if (q0 + 1 < Nq)
        out[(size_t)(q0 + 1) * LDIM + lane] = (D1 > 0.0f) ? o1 + b : 0.0f;
}

extern "C" void kernel_launch(void* const* d_in, const int* in_sizes, int n_in,
                              void* d_out, int out_size, void* d_ws, size_t ws_size,
                              hipStream_t stream) {
    const float* h_obs     = (const float*)d_in[0];
    const float* pos_obs   = (const float*)d_in[1];
    const float* pos_query = (const float*)d_in[2];
    const float* W1        = (const float*)d_in[3];
    const float* b1        = (const float*)d_in[4];
    const float* W2        = (const float*)d_in[5];
    // d_in[6] = b2: constant shift, cancels in softmax -> unused
    const float* Wv        = (const float*)d_in[7];
    const float* bv        = (const float*)d_in[8];
    const int* obs_mask    = (const int*)d_in[9];
    const int* obs_batch   = (const int*)d_in[10];
    const int* query_batch = (const int*)d_in[11];

    const int No  = in_sizes[1] / 3;
    const int Nq  = in_sizes[2] / 3;
    const int nC  = (No + 63) / 64;
    const int nT  = (Nq + QT - 1) / QT;

    // ws layout: acc (Nq*64) | den (Nq)
    float* acc = (float*)d_ws;
    float* den = acc + (size_t)Nq * LDIM;

    hipMemsetAsync(acc, 0, (size_t)Nq * (LDIM + 1) * sizeof(float), stream);

    dim3 g1(nT, nC);
    gano_accum<<<g1, 256, 0, stream>>>(
        h_obs, pos_obs, pos_query, W1, b1, W2,
        obs_mask, obs_batch, query_batch,
        acc, den, No, Nq);

    gano_norm<<<(Nq + 7) / 8, 256, 0, stream>>>(acc, den, Wv, bv, (float*)d_out, Nq);
}

// Round 13
// 32.174 us; speedup vs baseline: 1.5428x; 1.5428x over previous
//
#include <hip/hip_runtime.h>
#include <math.h>

#define LDIM 64
#define QT 32    // queries per tile
#define QW 8     // queries per wave
#define LOG2E 1.4426950408889634f

static __device__ __forceinline__ float fast_exp2(float x) {
#if __has_builtin(__builtin_amdgcn_exp2f)
    return __builtin_amdgcn_exp2f(x);
#else
    return exp2f(x);
#endif
}

static __device__ __forceinline__ float4 ld4(const float* p) {
    return *(const float4*)p;
}

// K1: one (64-obs chunk c, 32-query tile t) per block. R9's verified compute
// core (in-block B staging, logits lane=obs QW=8, no-max exp2, 8-deep h_obs
// PV with Wv deferred to K2). Output: PLAIN STORES of per-(t,c) partials --
// no atomics, no zeroing pass, no fences. part slots outside each tile's
// chunk window are never written NOR read (K2 recomputes the same window).
__global__ __launch_bounds__(256) void gano_accum(
    const float* __restrict__ h_obs,
    const float* __restrict__ pos_obs, const float* __restrict__ pos_query,
    const float* __restrict__ W1, const float* __restrict__ b1,
    const float* __restrict__ W2,
    const int* __restrict__ obs_mask, const int* __restrict__ obs_batch,
    const int* __restrict__ query_batch,
    float* __restrict__ partA, float* __restrict__ partD,
    int No, int Nq, int nC)
{
    const int c   = blockIdx.x;          // obs chunk (fast dim, as R7)
    const int t   = blockIdx.y;          // query tile
    const int q0  = t * QT;
    const int tid = threadIdx.x, lane = tid & 63, wid = tid >> 6;

    if ((c << 6) >= No) return;
    // batch-span intersection early-exit (both arrays sorted): 4 loads.
    // NOTE: must match K2's window [cs,ce] -- both are the same monotone
    // conditions (obs_batch[end_of_c] >= t_lo && obs_batch[start_of_c] <= t_hi).
    const int c_lo = obs_batch[c << 6];
    const int c_hi = obs_batch[min((c << 6) + 63, No - 1)];
    const int t_lo = query_batch[min(q0, Nq - 1)];
    const int t_hi = query_batch[min(q0 + QT - 1, Nq - 1)];
    if (c_lo > t_hi || c_hi < t_lo) return;

    __shared__ float4 B4[16][64];       // [g][o] obs-side preact chunk (16KB)
    __shared__ float4 a4[QT][16];       // [q][g] query-side preact (8KB)
    __shared__ float4 w2l[16];          // W2 * log2e
    __shared__ float4 qp4[QT];          // (x,y,z, batch+1)
    __shared__ float  e_lds[QT][LDIM];  // wave-private e rows (8KB)

    // ---- staging: a4 (2 entries/thread) ----
    #pragma unroll
    for (int rep = 0; rep < 2; ++rep) {
        const int i = tid + rep * 256;
        const int q = i >> 4, g = i & 15;
        const int qq = min(q0 + q, Nq - 1);
        const float px = pos_query[qq*3+0], py = pos_query[qq*3+1], pz = pos_query[qq*3+2];
        const float4 u0 = ld4(W1 + 0*LDIM + 4*g), u6 = ld4(W1 + 6*LDIM + 4*g);
        const float4 u1 = ld4(W1 + 1*LDIM + 4*g), u7 = ld4(W1 + 7*LDIM + 4*g);
        const float4 u2 = ld4(W1 + 2*LDIM + 4*g), u8 = ld4(W1 + 8*LDIM + 4*g);
        float4 r;
        r.x = fmaf(px, u0.x+u6.x, fmaf(py, u1.x+u7.x, pz*(u2.x+u8.x)));
        r.y = fmaf(px, u0.y+u6.y, fmaf(py, u1.y+u7.y, pz*(u2.y+u8.y)));
        r.z = fmaf(px, u0.z+u6.z, fmaf(py, u1.z+u7.z, pz*(u2.z+u8.z)));
        r.w = fmaf(px, u0.w+u6.w, fmaf(py, u1.w+u7.w, pz*(u2.w+u8.w)));
        a4[q][g] = r;
    }
    if (tid < 16) {
        const float4 w = ld4(W2 + 4 * tid);
        w2l[tid] = make_float4(w.x * LOG2E, w.y * LOG2E, w.z * LOG2E, w.w * LOG2E);
    }
    if (tid < QT) {
        const int q = min(q0 + tid, Nq - 1);
        qp4[tid] = make_float4(pos_query[q*3+0], pos_query[q*3+1], pos_query[q*3+2],
                               (float)(query_batch[q] + 1));
    }
    // ---- staging: B4 in-block, lane = obs, 4 g per wave (R9-verified) ----
    const int oo = (c << 6) + lane;
    float px = 0.f, py = 0.f, pz = 0.f, pcode = 0.f;
    if (oo < No) {
        px = pos_obs[oo*3+0]; py = pos_obs[oo*3+1]; pz = pos_obs[oo*3+2];
        pcode = obs_mask[oo] ? (float)(obs_batch[oo] + 1) : 0.0f;
    }
    #pragma unroll
    for (int k = 0; k < 4; ++k) {
        const int g = wid * 4 + k;
        const float4 b0 = ld4(b1 + 4*g);
        const float4 u3 = ld4(W1 + 3*LDIM + 4*g), u6 = ld4(W1 + 6*LDIM + 4*g);
        const float4 u4 = ld4(W1 + 4*LDIM + 4*g), u7 = ld4(W1 + 7*LDIM + 4*g);
        const float4 u5 = ld4(W1 + 5*LDIM + 4*g), u8 = ld4(W1 + 8*LDIM + 4*g);
        float4 r;
        r.x = fmaf(px, u3.x-u6.x, fmaf(py, u4.x-u7.x, fmaf(pz, u5.x-u8.x, b0.x)));
        r.y = fmaf(px, u3.y-u6.y, fmaf(py, u4.y-u7.y, fmaf(pz, u5.y-u8.y, b0.y)));
        r.z = fmaf(px, u3.z-u6.z, fmaf(py, u4.z-u7.z, fmaf(pz, u5.z-u8.z, b0.z)));
        r.w = fmaf(px, u3.w-u6.w, fmaf(py, u4.w-u7.w, fmaf(pz, u5.w-u8.w, b0.w)));
        B4[g][lane] = r;
    }
    __syncthreads();

    // ---- logits: lane = obs, 8 queries per wave ----
    float lg[QW];
    #pragma unroll
    for (int j = 0; j < QW; ++j) lg[j] = 0.0f;
    #pragma unroll
    for (int g = 0; g < 16; ++g) {
        const float4 Bv = B4[g][lane];
        const float4 wv = w2l[g];
        #pragma unroll
        for (int j = 0; j < QW; ++j) {
            const float4 a = a4[wid * QW + j][g];
            lg[j] = fmaf(fmaxf(a.x + Bv.x, 0.f), wv.x, lg[j]);
            lg[j] = fmaf(fmaxf(a.y + Bv.y, 0.f), wv.y, lg[j]);
            lg[j] = fmaf(fmaxf(a.z + Bv.z, 0.f), wv.z, lg[j]);
            lg[j] = fmaf(fmaxf(a.w + Bv.w, 0.f), wv.w, lg[j]);
        }
    }

    // ---- mask + direct exp2 (no-max softmax, validated R6-R12) ----
    float den_a[QW];
    #pragma unroll
    for (int j = 0; j < QW; ++j) {
        const float4 qp = qp4[wid * QW + j];
        const float dx = qp.x - px, dy = qp.y - py, dz = qp.z - pz;
        const float d2 = fmaf(dz, dz, fmaf(dy, dy, dx * dx));
        const bool valid = (pcode == qp.w) & (d2 <= 1.0f);
        const float e = valid ? fast_exp2(lg[j]) : 0.0f;
        e_lds[wid * QW + j][lane] = e;
        den_a[j] = e;
    }
    #pragma unroll
    for (int msk = 32; msk; msk >>= 1) {
        #pragma unroll
        for (int j = 0; j < QW; ++j) den_a[j] += __shfl_xor(den_a[j], msk, 64);
    }

    // ---- PV: lane = hidden-input dim k; h_obs direct, 8-deep (R9) ----
    float pacc[QW];
    #pragma unroll
    for (int j = 0; j < QW; ++j) pacc[j] = 0.0f;
    const float* Hc = h_obs + ((size_t)c << 12) + lane;
    if ((c << 6) + 64 <= No) {
        for (int o2 = 0; o2 < LDIM; o2 += 8) {
            const float v0 = Hc[(o2 + 0) << 6];
            const float v1 = Hc[(o2 + 1) << 6];
            const float v2 = Hc[(o2 + 2) << 6];
            const float v3 = Hc[(o2 + 3) << 6];
            const float v4 = Hc[(o2 + 4) << 6];
            const float v5 = Hc[(o2 + 5) << 6];
            const float v6 = Hc[(o2 + 6) << 6];
            const float v7 = Hc[(o2 + 7) << 6];
            #pragma unroll
            for (int j = 0; j < QW; ++j) {
                const float4 ea = *(const float4*)&e_lds[wid * QW + j][o2];
                const float4 eb = *(const float4*)&e_lds[wid * QW + j][o2 + 4];
                float s = pacc[j];
                s = fmaf(ea.x, v0, s); s = fmaf(ea.y, v1, s);
                s = fmaf(ea.z, v2, s); s = fmaf(ea.w, v3, s);
                s = fmaf(eb.x, v4, s); s = fmaf(eb.y, v5, s);
                s = fmaf(eb.z, v6, s); s = fmaf(eb.w, v7, s);
                pacc[j] = s;
            }
        }
    } else {  // tail chunk: clamp rows (e is 0 there)
        for (int o2 = 0; o2 < LDIM; ++o2) {
            const int orow = min((c << 6) + o2, No - 1);
            const float v = h_obs[((size_t)orow << 6) + lane];
            #pragma unroll
            for (int j = 0; j < QW; ++j)
                pacc[j] = fmaf(e_lds[wid * QW + j][o2], v, pacc[j]);
        }
    }

    // ---- writeback: plain coalesced stores (NO atomics) ----
    float* pa = partA + ((size_t)(t * nC + c) * QT) * LDIM;
    #pragma unroll
    for (int j = 0; j < QW; ++j)
        pa[(wid * QW + j) * LDIM + lane] = pacc[j];
    if (lane == 0) {
        float* pd = partD + (size_t)(t * nC + c) * QT;
        #pragma unroll
        for (int j = 0; j < QW; ++j) pd[wid * QW + j] = den_a[j];
    }
}

// K2: per query, sum the partials over the tile's chunk window (recomputed
// here with the SAME monotone conditions as K1's active test), normalize,
// Wv epilogue + bv. 4 waves x 2 queries per block.
__global__ __launch_bounds__(256) void gano_norm(
    const float* __restrict__ partA, const float* __restrict__ partD,
    const float* __restrict__ Wv, const float* __restrict__ bv,
    const int* __restrict__ obs_batch, const int* __restrict__ query_batch,
    float* __restrict__ out, int No, int Nq, int nC)
{
    const int tid = threadIdx.x, lane = tid & 63, wid = tid >> 6;
    const int q0 = blockIdx.x * 8 + wid * 2;
    if (q0 >= Nq) return;

    __shared__ float r_lds[4][2][LDIM];

    // tile window [cs, ce] (q0 and q0+1 are in the same 32-query tile)
    const int t = q0 / QT;
    const int t_lo = query_batch[min(t * QT, Nq - 1)];
    const int t_hi = query_batch[min(t * QT + QT - 1, Nq - 1)];
    int lo = 0, hi = nC;
    while (lo < hi) { int mid = (lo + hi) >> 1;
        if (obs_batch[min(mid * 64 + 63, No - 1)] < t_lo) lo = mid + 1; else hi = mid; }
    const int cs = lo;
    lo = 0; hi = nC;
    while (lo < hi) { int mid = (lo + hi) >> 1;
        if (obs_batch[min(mid * 64, No - 1)] <= t_hi) lo = mid + 1; else hi = mid; }
    const int ce = lo - 1;

    const int qi0 = q0 - t * QT;
    float A0 = 0.f, A1 = 0.f, D0 = 0.f, D1 = 0.f;
    for (int c = cs; c <= ce; ++c) {
        const size_t slot = (size_t)(t * nC + c);
        const float* pa = partA + slot * QT * LDIM;
        A0 += pa[(qi0 + 0) * LDIM + lane];
        D0 += partD[slot * QT + qi0 + 0];
        if (q0 + 1 < Nq) {
            A1 += pa[(qi0 + 1) * LDIM + lane];
            D1 += partD[slot * QT + qi0 + 1];
        }
    }

    const float rd0 = (D0 > 0.0f) ? 1.0f / D0 : 0.0f;
    const float rd1 = (D1 > 0.0f) ? 1.0f / D1 : 0.0f;
    r_lds[wid][0][lane] = A0 * rd0;
    r_lds[wid][1][lane] = A1 * rd1;
    // wave-private: no barrier needed
    float o0 = 0.f, o1 = 0.f;
    #pragma unroll 8
    for (int k = 0; k < LDIM; ++k) {
        const float w = Wv[(k << 6) + lane];
        o0 = fmaf(r_lds[wid][0][k], w, o0);
        o1 = fmaf(r_lds[wid][1][k], w, o1);
    }
    const float b = bv[lane];
    out[(size_t)q0 * LDIM + lane] = (D0 > 0.0f) ? o0 + b : 0.0f;
    if (q0 + 1 < Nq)
        out[(size_t)(q0 + 1) * LDIM + lane] = (D1 > 0.0f) ? o1 + b : 0.0f;
}

extern "C" void kernel_launch(void* const* d_in, const int* in_sizes, int n_in,
                              void* d_out, int out_size, void* d_ws, size_t ws_size,
                              hipStream_t stream) {
    const float* h_obs     = (const float*)d_in[0];
    const float* pos_obs   = (const float*)d_in[1];
    const float* pos_query = (const float*)d_in[2];
    const float* W1        = (const float*)d_in[3];
    const float* b1        = (const float*)d_in[4];
    const float* W2        = (const float*)d_in[5];
    // d_in[6] = b2: constant shift, cancels in softmax -> unused
    const float* Wv        = (const float*)d_in[7];
    const float* bv        = (const float*)d_in[8];
    const int* obs_mask    = (const int*)d_in[9];
    const int* obs_batch   = (const int*)d_in[10];
    const int* query_batch = (const int*)d_in[11];

    const int No  = in_sizes[1] / 3;
    const int Nq  = in_sizes[2] / 3;
    const int nC  = (No + 63) / 64;
    const int nT  = (Nq + QT - 1) / QT;

    // ws layout: partA (nT*nC*QT*64 f = 8.4 MB) | partD (nT*nC*QT f)
    float* partA = (float*)d_ws;
    float* partD = partA + (size_t)nT * nC * QT * LDIM;

    dim3 g1(nC, nT);
    gano_accum<<<g1, 256, 0, stream>>>(
        h_obs, pos_obs, pos_query, W1, b1, W2,
        obs_mask, obs_batch, query_batch,
        partA, partD, No, Nq, nC);

    gano_norm<<<(Nq + 7) / 8, 256, 0, stream>>>(
        partA, partD, Wv, bv, obs_batch, query_batch,
        (float*)d_out, No, Nq, nC);
}